// Round 6
// baseline (3846.428 us; speedup 1.0000x reference)
//
#include <hip/hip_runtime.h>
#include <hip/hip_bf16.h>

#define DIM 768
#define NH  12
#define HW  64
#define BB  32
#define NV  100
#define NQ  32
#define NA  32

#define S1 (BB * NV * DIM)         // 2457600
#define S2 (S1 + BB * NQ * DIM)    // 3244032

// Store f32, rounded through bf16 to match the harness's bf16-rounded
// expected values exactly (also correct if compared at full precision).
__device__ __forceinline__ float bf16r(float x) {
    return __bfloat162float(__float2bfloat16(x));
}

// ---------------------------------------------------------------------------
// Kernel A: one block per (b,h). Projects head slices in-kernel (LDS), then
// LITERAL reference softmax over all NV*NQ*NA entries; writes marginals.
//   s = scale*<vh, qh*ah> - 10000*vm - 10000*qm - 10000*am
//   m = max over ALL entries; e = expf(s-m); Z = sum ALL e
//   pv[v]=sum_{q,a} e/Z ; pq, pa likewise.
// ---------------------------------------------------------------------------
__global__ __launch_bounds__(256) void attn_marginals_literal(
    const float* __restrict__ vin, const float* __restrict__ qin, const float* __restrict__ ain,
    const int* __restrict__ vmask, const int* __restrict__ qmask, const int* __restrict__ amask,
    const float* __restrict__ Wv, const float* __restrict__ bv,
    const float* __restrict__ Wq, const float* __restrict__ bq,
    const float* __restrict__ Wa, const float* __restrict__ ba,
    float* __restrict__ pvg, float* __restrict__ pqg, float* __restrict__ pag)
{
    const int b = blockIdx.x / NH, h = blockIdx.x % NH;
    const int tid = threadIdx.x;
    __shared__ float vph[NV][HW];
    __shared__ float qph[NQ][HW];
    __shared__ float aph[NA][HW];
    __shared__ float red[256];
    __shared__ float pv_sh[NV], pq_sh[NQ], pa_sh[NA];
    __shared__ float vmf[NV], qmf[NQ], amf[NA];
    __shared__ float msh, zsh;

    for (int e = tid; e < NV * HW; e += 256) {
        int v = e >> 6, w = e & 63;
        float acc = bv[h * HW + w];
        const float* xr = vin + (size_t)(b * NV + v) * DIM;
        const float* wc = Wv + h * HW + w;
        for (int k = 0; k < DIM; ++k) acc = fmaf(xr[k], wc[(size_t)k * DIM], acc);
        vph[v][w] = acc;
    }
    for (int e = tid; e < NQ * HW; e += 256) {
        int s = e >> 6, w = e & 63;
        {
            float acc = bq[h * HW + w];
            const float* xr = qin + (size_t)(b * NQ + s) * DIM;
            const float* wc = Wq + h * HW + w;
            for (int k = 0; k < DIM; ++k) acc = fmaf(xr[k], wc[(size_t)k * DIM], acc);
            qph[s][w] = acc;
        }
        {
            float acc = ba[h * HW + w];
            const float* xr = ain + (size_t)(b * NA + s) * DIM;
            const float* wc = Wa + h * HW + w;
            for (int k = 0; k < DIM; ++k) acc = fmaf(xr[k], wc[(size_t)k * DIM], acc);
            aph[s][w] = acc;
        }
    }
    if (tid < NV) { vmf[tid] = 10000.f * (float)vmask[b * NV + tid]; pv_sh[tid] = 0.f; }
    if (tid < NQ) { qmf[tid] = 10000.f * (float)qmask[b * NQ + tid]; pq_sh[tid] = 0.f; }
    if (tid < NA) { amf[tid] = 10000.f * (float)amask[b * NA + tid]; pa_sh[tid] = 0.f; }
    if (tid == 0) zsh = 0.f;
    __syncthreads();

    const float scale = 0.125f;   // 1/sqrt(64)

    // pass A: literal global max over ALL entries
    float lmax = -3.4e38f;
    for (int e = tid; e < NV * NQ * NA; e += 256) {
        int v = e / (NQ * NA);
        int r = e - v * (NQ * NA);
        int q = r >> 5, a = r & 31;
        float s = 0.f;
        for (int w = 0; w < HW; ++w) s = fmaf(vph[v][w], qph[q][w] * aph[a][w], s);
        s = s * scale - vmf[v] - qmf[q] - amf[a];
        lmax = fmaxf(lmax, s);
    }
    red[tid] = lmax;
    __syncthreads();
    if (tid == 0) {
        float m = red[0];
        for (int i = 1; i < 256; ++i) m = fmaxf(m, red[i]);
        msh = m;
    }
    __syncthreads();
    const float m = msh;

    // pass B: exp(s - m), total Z, marginal accumulation
    float zloc = 0.f;
    for (int e = tid; e < NV * NQ * NA; e += 256) {
        int v = e / (NQ * NA);
        int r = e - v * (NQ * NA);
        int q = r >> 5, a = r & 31;
        float s = 0.f;
        for (int w = 0; w < HW; ++w) s = fmaf(vph[v][w], qph[q][w] * aph[a][w], s);
        s = s * scale - vmf[v] - qmf[q] - amf[a];
        float ev = expf(s - m);
        zloc += ev;
        atomicAdd(&pv_sh[v], ev);
        atomicAdd(&pq_sh[q], ev);
        atomicAdd(&pa_sh[a], ev);
    }
    atomicAdd(&zsh, zloc);
    __syncthreads();

    const float invZ = 1.0f / zsh;
    if (tid < NV) pvg[(size_t)blockIdx.x * NV + tid] = pv_sh[tid] * invZ;
    if (tid < NQ) pqg[(size_t)blockIdx.x * NQ + tid] = pq_sh[tid] * invZ;
    if (tid < NA) pag[(size_t)blockIdx.x * NA + tid] = pa_sh[tid] * invZ;
}

// ---------------------------------------------------------------------------
// Kernel B: one block per (b,s) row. Recomputes proj row in LDS, then the
// out-projection, scales by the marginal, stores **f32** (bf16-rounded).
// ---------------------------------------------------------------------------
__global__ __launch_bounds__(256) void out_literal(
    const float* __restrict__ X,
    const float* __restrict__ W1, const float* __restrict__ b1,
    const float* __restrict__ W2, const float* __restrict__ b2,
    const float* __restrict__ marg, int S,
    float* __restrict__ outsec)
{
    const int row = blockIdx.x;            // b*S + s
    const int b = row / S, s = row - b * S;
    const int tid = threadIdx.x;
    __shared__ float xr[DIM];
    __shared__ float pr[DIM];

    for (int i = tid; i < DIM; i += 256) xr[i] = X[(size_t)row * DIM + i];
    __syncthreads();

    for (int c = tid; c < DIM; c += 256) {
        float acc = b1[c];
        const float* wc = W1 + c;
        for (int k = 0; k < DIM; ++k) acc = fmaf(xr[k], wc[(size_t)k * DIM], acc);
        pr[c] = acc;
    }
    __syncthreads();

    for (int c = tid; c < DIM; c += 256) {
        float acc = b2[c];
        const float* wc = W2 + c;
        for (int k = 0; k < DIM; ++k) acc = fmaf(pr[k], wc[(size_t)k * DIM], acc);
        const int h = c >> 6;
        const float mg = marg[((size_t)b * NH + h) * S + s];
        outsec[(size_t)row * DIM + c] = bf16r(acc * mg);
    }
}

// ---------------------------------------------------------------------------
extern "C" void kernel_launch(void* const* d_in, const int* in_sizes, int n_in,
                              void* d_out, int out_size, void* d_ws, size_t ws_size,
                              hipStream_t stream)
{
    const float* v     = (const float*)d_in[0];
    const float* q     = (const float*)d_in[1];
    const float* a     = (const float*)d_in[2];
    const int*   vmask = (const int*)d_in[3];
    const int*   qmask = (const int*)d_in[4];
    const int*   amask = (const int*)d_in[5];
    const float* Wv  = (const float*)d_in[6];
    const float* bv  = (const float*)d_in[7];
    const float* Wq  = (const float*)d_in[8];
    const float* bq  = (const float*)d_in[9];
    const float* Wa  = (const float*)d_in[10];
    const float* ba  = (const float*)d_in[11];
    const float* Wvo = (const float*)d_in[12];
    const float* bvo = (const float*)d_in[13];
    const float* Wqo = (const float*)d_in[14];
    const float* bqo = (const float*)d_in[15];
    const float* Wao = (const float*)d_in[16];
    const float* bao = (const float*)d_in[17];
    float* out = (float*)d_out;          // reference output dtype is FLOAT32

    float* pv = (float*)d_ws;            // BB*NH*NV = 38400
    float* pq = pv + BB * NH * NV;       // 12288
    float* pa = pq + BB * NH * NQ;       // 12288

    attn_marginals_literal<<<dim3(BB * NH), dim3(256), 0, stream>>>(
        v, q, a, vmask, qmask, amask, Wv, bv, Wq, bq, Wa, ba, pv, pq, pa);

    out_literal<<<dim3(BB * NV), dim3(256), 0, stream>>>(
        v, Wv, bv, Wvo, bvo, pv, NV, out);
    out_literal<<<dim3(BB * NQ), dim3(256), 0, stream>>>(
        q, Wq, bq, Wqo, bqo, pq, NQ, out + S1);
    out_literal<<<dim3(BB * NA), dim3(256), 0, stream>>>(
        a, Wa, ba, Wao, bao, pa, NA, out + S2);
}

// Round 7
// 428.188 us; speedup vs baseline: 8.9830x; 8.9830x over previous
//
#include <hip/hip_runtime.h>
#include <hip/hip_bf16.h>

#define DIM 768
#define NH  12
#define HW  64
#define BB  32
#define NV  100
#define NQ  32
#define NA  32

#define VP_ELEMS (BB * NV * DIM)   // 2457600
#define QP_ELEMS (BB * NQ * DIM)   // 786432
#define AP_ELEMS (BB * NA * DIM)   // 786432
#define S1 (VP_ELEMS)
#define S2 (S1 + QP_ELEMS)

__device__ __forceinline__ float bf16r(float x) {
    return __bfloat162float(__float2bfloat16(x));
}

// ---------------------------------------------------------------------------
// Tiled GEMM: Y[M x 768] = X[M x 768] @ W[768 x 768] + bias, fp32.
// 64x64 tile / block, 256 threads, 4x4 per thread, K-tile 16.
// M % 64 == 0 (3200 or 1024), N = K = 768 -> no guards.
// ---------------------------------------------------------------------------
__global__ __launch_bounds__(256) void gemm_bias_f32(
    const float* __restrict__ X, const float* __restrict__ W,
    const float* __restrict__ bias, float* __restrict__ Y)
{
    __shared__ float As[16][68];   // [k][m], padded
    __shared__ float Bs[16][68];   // [k][n], padded
    const int tid = threadIdx.x;
    const int bm = blockIdx.y * 64;
    const int bn = blockIdx.x * 64;
    const int tx = tid & 15, ty = tid >> 4;
    const int la_m = tid >> 2,  la_k = (tid & 3) << 2;
    const int lb_k = tid >> 4,  lb_n = (tid & 15) << 2;

    float acc[4][4] = {{0.f}};

    for (int k0 = 0; k0 < DIM; k0 += 16) {
        const float4 av = *(const float4*)&X[(bm + la_m) * DIM + k0 + la_k];
        const float4 bv = *(const float4*)&W[(k0 + lb_k) * DIM + bn + lb_n];
        __syncthreads();
        As[la_k + 0][la_m] = av.x;
        As[la_k + 1][la_m] = av.y;
        As[la_k + 2][la_m] = av.z;
        As[la_k + 3][la_m] = av.w;
        *(float4*)&Bs[lb_k][lb_n] = bv;
        __syncthreads();
#pragma unroll
        for (int kk = 0; kk < 16; ++kk) {
            float a[4], b[4];
            *(float4*)a = *(const float4*)&As[kk][ty << 2];
            *(float4*)b = *(const float4*)&Bs[kk][tx << 2];
#pragma unroll
            for (int i = 0; i < 4; ++i)
#pragma unroll
                for (int j = 0; j < 4; ++j)
                    acc[i][j] += a[i] * b[j];
        }
    }

#pragma unroll
    for (int i = 0; i < 4; ++i) {
        float4 o;
        o.x = acc[i][0] + bias[bn + (tx << 2) + 0];
        o.y = acc[i][1] + bias[bn + (tx << 2) + 1];
        o.z = acc[i][2] + bias[bn + (tx << 2) + 2];
        o.w = acc[i][3] + bias[bn + (tx << 2) + 3];
        *(float4*)&Y[(bm + (ty << 2) + i) * DIM + bn + (tx << 2)] = o;
    }
}

// ---------------------------------------------------------------------------
// Out-projection GEMM with fused marginal epilogue:
//   out[row, col] = (P[row,:] @ Wo[:,col] + bo[col]) * marg[(b*NH + col/64)*S + s]
// row = b*S + s. Tile N=64 => h = bn>>6 uniform per block. f32 store, bf16-rounded.
// ---------------------------------------------------------------------------
__global__ __launch_bounds__(256) void gemm_out_fused(
    const float* __restrict__ P, const float* __restrict__ Wo,
    const float* __restrict__ bo, const float* __restrict__ marg,
    float* __restrict__ out, int S)
{
    __shared__ float As[16][68];
    __shared__ float Bs[16][68];
    const int tid = threadIdx.x;
    const int bm = blockIdx.y * 64;
    const int bn = blockIdx.x * 64;
    const int h  = bn >> 6;
    const int tx = tid & 15, ty = tid >> 4;
    const int la_m = tid >> 2,  la_k = (tid & 3) << 2;
    const int lb_k = tid >> 4,  lb_n = (tid & 15) << 2;

    float acc[4][4] = {{0.f}};

    for (int k0 = 0; k0 < DIM; k0 += 16) {
        const float4 av = *(const float4*)&P[(bm + la_m) * DIM + k0 + la_k];
        const float4 bv = *(const float4*)&Wo[(k0 + lb_k) * DIM + bn + lb_n];
        __syncthreads();
        As[la_k + 0][la_m] = av.x;
        As[la_k + 1][la_m] = av.y;
        As[la_k + 2][la_m] = av.z;
        As[la_k + 3][la_m] = av.w;
        *(float4*)&Bs[lb_k][lb_n] = bv;
        __syncthreads();
#pragma unroll
        for (int kk = 0; kk < 16; ++kk) {
            float a[4], b[4];
            *(float4*)a = *(const float4*)&As[kk][ty << 2];
            *(float4*)b = *(const float4*)&Bs[kk][tx << 2];
#pragma unroll
            for (int i = 0; i < 4; ++i)
#pragma unroll
                for (int j = 0; j < 4; ++j)
                    acc[i][j] += a[i] * b[j];
        }
    }

#pragma unroll
    for (int i = 0; i < 4; ++i) {
        const int row = bm + (ty << 2) + i;
        const int b = row / S, s = row - b * S;
        const float mg = marg[(b * NH + h) * S + s];
        float4 o;
        o.x = bf16r((acc[i][0] + bo[bn + (tx << 2) + 0]) * mg);
        o.y = bf16r((acc[i][1] + bo[bn + (tx << 2) + 1]) * mg);
        o.z = bf16r((acc[i][2] + bo[bn + (tx << 2) + 2]) * mg);
        o.w = bf16r((acc[i][3] + bo[bn + (tx << 2) + 3]) * mg);
        *(float4*)&out[row * DIM + bn + (tx << 2)] = o;
    }
}

// ---------------------------------------------------------------------------
// Attention marginals (round-1 shuffle version — bit-validated vs literal).
// One block per (b,h), 1024 threads; thread t owns (q=t>>5, a=t&31).
// No atomics: wave shuffle reductions + per-wave LDS partials.
// ---------------------------------------------------------------------------
__global__ __launch_bounds__(1024) void attn_marginals(
    const float* __restrict__ vp, const float* __restrict__ qp, const float* __restrict__ ap,
    const int* __restrict__ vmask, const int* __restrict__ qmask, const int* __restrict__ amask,
    float* __restrict__ pvg, float* __restrict__ pqg, float* __restrict__ pag)
{
    const int b = blockIdx.x / NH;
    const int h = blockIdx.x % NH;
    __shared__ float vhs[NV][HW];
    __shared__ float qhs[NQ][HW];
    __shared__ float ahs[NA][HW];
    __shared__ float pvw[16][NV];
    __shared__ float pq_s[NQ];
    __shared__ float pa_w[16][NA];
    __shared__ int   vm[NV];
    __shared__ float zsh;
    const int tid = threadIdx.x;

    for (int i = tid; i < NV * HW; i += 1024) {
        int v = i >> 6, w = i & 63;
        vhs[v][w] = vp[(b * NV + v) * DIM + h * HW + w];
    }
    for (int i = tid; i < NQ * HW; i += 1024) {
        int s = i >> 6, w = i & 63;
        qhs[s][w] = qp[(b * NQ + s) * DIM + h * HW + w];
        ahs[s][w] = ap[(b * NA + s) * DIM + h * HW + w];
    }
    if (tid < NV) vm[tid] = vmask[b * NV + tid];

    const int q = tid >> 5, a = tid & 31;
    const int pm = qmask[b * NQ + q] | amask[b * NA + a];
    __syncthreads();

    float g[HW];
#pragma unroll
    for (int w = 0; w < HW; ++w) g[w] = qhs[q][w] * ahs[a][w];

    const int wid = tid >> 6, lane = tid & 63;
    const float scale = 0.125f;  // 1/sqrt(64)
    float zacc = 0.f;

    for (int v = 0; v < NV; ++v) {
        if (vm[v]) {                       // wave-uniform skip
            if (lane == 0) pvw[wid][v] = 0.f;
            continue;
        }
        float s = 0.f;
#pragma unroll
        for (int w = 0; w < HW; ++w) s += vhs[v][w] * g[w];
        float e = pm ? 0.f : __expf(s * scale);
        zacc += e;
        float r = e;
        r += __shfl_xor(r, 32);
        r += __shfl_xor(r, 16);
        r += __shfl_xor(r, 8);
        r += __shfl_xor(r, 4);
        r += __shfl_xor(r, 2);
        r += __shfl_xor(r, 1);
        if (lane == 0) pvw[wid][v] = r;
    }

    // pq: lanes sharing q are a contiguous half-wave (32 lanes)
    float pqp = zacc;
    pqp += __shfl_xor(pqp, 16);
    pqp += __shfl_xor(pqp, 8);
    pqp += __shfl_xor(pqp, 4);
    pqp += __shfl_xor(pqp, 2);
    pqp += __shfl_xor(pqp, 1);
    if ((lane & 31) == 0) pq_s[q] = pqp;   // each q written exactly once

    // pa: lane l and l^32 share a
    float pap = zacc + __shfl_xor(zacc, 32);
    if (lane < 32) pa_w[wid][lane] = pap;
    __syncthreads();

    float pvf = 0.f, paf = 0.f;
    if (tid < NV) {
#pragma unroll
        for (int i = 0; i < 16; ++i) pvf += pvw[i][tid];
    }
    if (tid >= 128 && tid < 128 + NA) {
        int aa = tid - 128;
#pragma unroll
        for (int i = 0; i < 16; ++i) paf += pa_w[i][aa];
    }
    if (wid == 3) {  // Z = sum of pq_s
        float zv = (lane < NQ) ? pq_s[lane] : 0.f;
        zv += __shfl_xor(zv, 32);
        zv += __shfl_xor(zv, 16);
        zv += __shfl_xor(zv, 8);
        zv += __shfl_xor(zv, 4);
        zv += __shfl_xor(zv, 2);
        zv += __shfl_xor(zv, 1);
        if (lane == 0) zsh = zv;
    }
    __syncthreads();
    const float invZ = 1.0f / zsh;
    if (tid < NV) pvg[blockIdx.x * NV + tid] = pvf * invZ;
    if (tid >= 128 && tid < 128 + NA) pag[blockIdx.x * NA + (tid - 128)] = paf * invZ;
    if (tid >= 192 && tid < 192 + NQ) pqg[blockIdx.x * NQ + (tid - 192)] = pq_s[tid - 192] * invZ;
}

// ---------------------------------------------------------------------------
extern "C" void kernel_launch(void* const* d_in, const int* in_sizes, int n_in,
                              void* d_out, int out_size, void* d_ws, size_t ws_size,
                              hipStream_t stream)
{
    const float* v     = (const float*)d_in[0];
    const float* q     = (const float*)d_in[1];
    const float* a     = (const float*)d_in[2];
    const int*   vmask = (const int*)d_in[3];
    const int*   qmask = (const int*)d_in[4];
    const int*   amask = (const int*)d_in[5];
    const float* Wv  = (const float*)d_in[6];
    const float* bv  = (const float*)d_in[7];
    const float* Wq  = (const float*)d_in[8];
    const float* bq  = (const float*)d_in[9];
    const float* Wa  = (const float*)d_in[10];
    const float* ba  = (const float*)d_in[11];
    const float* Wvo = (const float*)d_in[12];
    const float* bvo = (const float*)d_in[13];
    const float* Wqo = (const float*)d_in[14];
    const float* bqo = (const float*)d_in[15];
    const float* Wao = (const float*)d_in[16];
    const float* bao = (const float*)d_in[17];
    float* out = (float*)d_out;          // reference output dtype is FLOAT32

    float* ws = (float*)d_ws;
    float* vp = ws;                    // 2457600
    float* qp = vp + VP_ELEMS;         // 786432
    float* ap = qp + QP_ELEMS;         // 786432
    float* pv = ap + AP_ELEMS;         // 38400
    float* pq = pv + BB * NH * NV;     // 12288
    float* pa = pq + BB * NH * NQ;     // 12288
    // total ws: 16.4 MB

    dim3 blk(256);
    dim3 gv(DIM / 64, (BB * NV) / 64);   // 12 x 50
    dim3 gq(DIM / 64, (BB * NQ) / 64);   // 12 x 16

    gemm_bias_f32<<<gv, blk, 0, stream>>>(v, Wv, bv, vp);
    gemm_bias_f32<<<gq, blk, 0, stream>>>(q, Wq, bq, qp);
    gemm_bias_f32<<<gq, blk, 0, stream>>>(a, Wa, ba, ap);

    attn_marginals<<<dim3(BB * NH), dim3(1024), 0, stream>>>(
        vp, qp, ap, vmask, qmask, amask, pv, pq, pa);

    gemm_out_fused<<<gv, blk, 0, stream>>>(vp, Wvo, bvo, pv, out, NV);
    gemm_out_fused<<<gq, blk, 0, stream>>>(qp, Wqo, bqo, pq, out + S1, NQ);
    gemm_out_fused<<<gq, blk, 0, stream>>>(ap, Wao, bao, pa, out + S2, NA);
}

// Round 8
// 237.098 us; speedup vs baseline: 16.2230x; 1.8060x over previous
//
#include <hip/hip_runtime.h>
#include <hip/hip_bf16.h>

#define DIM 768
#define NH  12
#define HW  64
#define BB  32
#define NV  100
#define NQ  32
#define NA  32

#define VP_ELEMS (BB * NV * DIM)   // 2457600
#define QP_ELEMS (BB * NQ * DIM)   // 786432
#define AP_ELEMS (BB * NA * DIM)   // 786432
#define S1 (VP_ELEMS)
#define S2 (S1 + QP_ELEMS)
#define STOT (S2 + AP_ELEMS)       // 4030464
#define WELEMS (DIM * DIM)         // 589824

typedef __attribute__((ext_vector_type(8))) short     bf16x8;
typedef __attribute__((ext_vector_type(8))) unsigned short u16x8;
typedef __attribute__((ext_vector_type(4))) float     f32x4;

__device__ __forceinline__ float bf16r(float x) {
    return __bfloat162float(__float2bfloat16(x));
}
__device__ __forceinline__ unsigned short f2bu(float x) {
    __hip_bfloat16 h = __float2bfloat16(x);
    return *reinterpret_cast<unsigned short*>(&h);
}
__device__ __forceinline__ float bu2f(unsigned short u) {
    __hip_bfloat16 h;
    *reinterpret_cast<unsigned short*>(&h) = u;
    return __bfloat162float(h);
}

// ---------------------------------------------------------------------------
// Convert v|q|a (f32) -> contiguous bf16 buffer. 4 elems / thread.
// ---------------------------------------------------------------------------
__global__ __launch_bounds__(256) void conv_x(
    const float* __restrict__ v, const float* __restrict__ q,
    const float* __restrict__ a, unsigned short* __restrict__ dst)
{
    int idx = (blockIdx.x * 256 + threadIdx.x) * 4;
    if (idx >= STOT) return;
    const float* src; int off;
    if (idx < S1)      { src = v; off = idx; }
    else if (idx < S2) { src = q; off = idx - S1; }
    else               { src = a; off = idx - S2; }
    float4 f = *(const float4*)&src[off];
    ushort4 u;
    u.x = f2bu(f.x); u.y = f2bu(f.y); u.z = f2bu(f.z); u.w = f2bu(f.w);
    *(ushort4*)&dst[idx] = u;
}

// ---------------------------------------------------------------------------
// Convert 6 weights (f32, [k][n]) -> bf16 TRANSPOSED [n][k], via 64x64 LDS
// tiles. 6 * 144 tiles. Coalesced read + coalesced write.
// ---------------------------------------------------------------------------
__global__ __launch_bounds__(256) void conv_wT(
    const float* __restrict__ W0, const float* __restrict__ W1,
    const float* __restrict__ W2, const float* __restrict__ W3,
    const float* __restrict__ W4, const float* __restrict__ W5,
    unsigned short* __restrict__ WtAll)
{
    const int widx = blockIdx.x / 144;
    const int t    = blockIdx.x % 144;
    const int tr = t / 12, tc = t % 12;
    const float* W = (widx == 0) ? W0 : (widx == 1) ? W1 : (widx == 2) ? W2
                   : (widx == 3) ? W3 : (widx == 4) ? W4 : W5;
    unsigned short* Wt = WtAll + (size_t)widx * WELEMS;

    __shared__ float tile[64][65];
    const int c = threadIdx.x & 63, r4 = threadIdx.x >> 6;
#pragma unroll
    for (int it = 0; it < 16; ++it) {
        int r = it * 4 + r4;
        tile[r][c] = W[(size_t)(tr * 64 + r) * DIM + tc * 64 + c];
    }
    __syncthreads();
#pragma unroll
    for (int it = 0; it < 16; ++it) {
        int r = it * 4 + r4;   // output n-offset
        Wt[(size_t)(tc * 64 + r) * DIM + tr * 64 + c] = f2bu(tile[c][r]);
    }
}

// ---------------------------------------------------------------------------
// Fused MFMA GEMM over 3 pointer-sets (v/q/a). Y = X @ W + bias.
// X: [M][768] bf16 row-major. Wt: [n][k] bf16 (transposed weight).
// 128x128 tile, 256 thr = 2x2 waves, each wave 4x4 frags of 16x16, BK=32.
// OUT=0: write bf16 Y.  OUT=1: write f32 out, scaled by marginal, bf16-rounded.
// Tiles: set0 25x6=[0,150), set1 8x6=[150,198), set2 8x6=[198,246).
// ---------------------------------------------------------------------------
template <int OUT>
__global__ __launch_bounds__(256) void gemm_mfma(
    const unsigned short* __restrict__ X0, const unsigned short* __restrict__ X1,
    const unsigned short* __restrict__ X2,
    const unsigned short* __restrict__ W0, const unsigned short* __restrict__ W1,
    const unsigned short* __restrict__ W2,
    const float* __restrict__ c0, const float* __restrict__ c1, const float* __restrict__ c2,
    unsigned short* __restrict__ Y0, unsigned short* __restrict__ Y1,
    unsigned short* __restrict__ Y2,
    float* __restrict__ O0, float* __restrict__ O1, float* __restrict__ O2,
    const float* __restrict__ m0, const float* __restrict__ m1, const float* __restrict__ m2)
{
    __shared__ unsigned short As[128 * 32];
    __shared__ unsigned short Bs[128 * 32];

    const int t = blockIdx.x;
    int set, loc;
    if (t < 150)      { set = 0; loc = t; }
    else if (t < 198) { set = 1; loc = t - 150; }
    else              { set = 2; loc = t - 198; }
    const int tm = loc / 6, tn = loc % 6;

    const unsigned short* X  = (set == 0) ? X0 : (set == 1) ? X1 : X2;
    const unsigned short* Wt = (set == 0) ? W0 : (set == 1) ? W1 : W2;
    const float* bias        = (set == 0) ? c0 : (set == 1) ? c1 : c2;
    unsigned short* Y        = (set == 0) ? Y0 : (set == 1) ? Y1 : Y2;
    float* Out               = (set == 0) ? O0 : (set == 1) ? O1 : O2;
    const float* mg          = (set == 0) ? m0 : (set == 1) ? m1 : m2;
    const int S              = (set == 0) ? NV : NQ;

    const int tid  = threadIdx.x;
    const int lane = tid & 63;
    const int wave = tid >> 6;
    const int wr = wave >> 1, wc = wave & 1;
    const int bm = tm * 128, bn = tn * 128;

    // staging coords: 2 iters x (row = li>>2, kc = (li&3)*8)
    const int srow0 = tid >> 2, skc = (tid & 3) << 3;

    f32x4 acc[4][4] = {};

    for (int k0 = 0; k0 < DIM; k0 += 32) {
        *(u16x8*)&As[srow0 * 32 + skc] =
            *(const u16x8*)&X[(size_t)(bm + srow0) * DIM + k0 + skc];
        *(u16x8*)&As[(srow0 + 64) * 32 + skc] =
            *(const u16x8*)&X[(size_t)(bm + srow0 + 64) * DIM + k0 + skc];
        *(u16x8*)&Bs[srow0 * 32 + skc] =
            *(const u16x8*)&Wt[(size_t)(bn + srow0) * DIM + k0 + skc];
        *(u16x8*)&Bs[(srow0 + 64) * 32 + skc] =
            *(const u16x8*)&Wt[(size_t)(bn + srow0 + 64) * DIM + k0 + skc];
        __syncthreads();

        bf16x8 af[4], bfr[4];
#pragma unroll
        for (int mi = 0; mi < 4; ++mi)
            af[mi] = *(const bf16x8*)&As[(wr * 64 + mi * 16 + (lane & 15)) * 32 + (lane >> 4) * 8];
#pragma unroll
        for (int ni = 0; ni < 4; ++ni)
            bfr[ni] = *(const bf16x8*)&Bs[(wc * 64 + ni * 16 + (lane & 15)) * 32 + (lane >> 4) * 8];
#pragma unroll
        for (int mi = 0; mi < 4; ++mi)
#pragma unroll
            for (int ni = 0; ni < 4; ++ni)
                acc[mi][ni] = __builtin_amdgcn_mfma_f32_16x16x32_bf16(
                    af[mi], bfr[ni], acc[mi][ni], 0, 0, 0);
        __syncthreads();
    }

    // epilogue. D layout: col = lane&15, row = (lane>>4)*4 + r  (m89-verified)
    const int h = (bn + wc * 64) >> 6;   // uniform per wave (64-col span)
#pragma unroll
    for (int mi = 0; mi < 4; ++mi) {
#pragma unroll
        for (int r = 0; r < 4; ++r) {
            const int m = bm + wr * 64 + mi * 16 + (lane >> 4) * 4 + r;
            float mgv = 0.f;
            if (OUT) {
                const int bb = m / S, ss = m - bb * S;
                mgv = mg[(bb * NH + h) * S + ss];
            }
#pragma unroll
            for (int ni = 0; ni < 4; ++ni) {
                const int n = bn + wc * 64 + ni * 16 + (lane & 15);
                const float val = acc[mi][ni][r] + bias[n];
                if (!OUT) Y[(size_t)m * DIM + n] = f2bu(val);
                else      Out[(size_t)m * DIM + n] = bf16r(val * mgv);
            }
        }
    }
}

// ---------------------------------------------------------------------------
// Attention marginals (validated logic; bf16 inputs, padded LDS).
// One block per (b,h), 1024 threads; thread t owns (q=t>>5, a=t&31).
// ---------------------------------------------------------------------------
__global__ __launch_bounds__(1024) void attn_marginals(
    const unsigned short* __restrict__ vp, const unsigned short* __restrict__ qp,
    const unsigned short* __restrict__ ap,
    const int* __restrict__ vmask, const int* __restrict__ qmask, const int* __restrict__ amask,
    float* __restrict__ pvg, float* __restrict__ pqg, float* __restrict__ pag)
{
    const int b = blockIdx.x / NH;
    const int h = blockIdx.x % NH;
    __shared__ float vhs[NV][HW + 1];
    __shared__ float qhs[NQ][HW + 1];
    __shared__ float ahs[NA][HW + 1];
    __shared__ float pvw[16][NV];
    __shared__ float pq_s[NQ];
    __shared__ float pa_w[16][NA];
    __shared__ int   vm[NV];
    __shared__ float zsh;
    const int tid = threadIdx.x;

    for (int i = tid; i < NV * HW; i += 1024) {
        int v = i >> 6, w = i & 63;
        vhs[v][w] = bu2f(vp[(size_t)(b * NV + v) * DIM + h * HW + w]);
    }
    for (int i = tid; i < NQ * HW; i += 1024) {
        int s = i >> 6, w = i & 63;
        qhs[s][w] = bu2f(qp[(size_t)(b * NQ + s) * DIM + h * HW + w]);
        ahs[s][w] = bu2f(ap[(size_t)(b * NA + s) * DIM + h * HW + w]);
    }
    if (tid < NV) vm[tid] = vmask[b * NV + tid];

    const int q = tid >> 5, a = tid & 31;
    const int pm = qmask[b * NQ + q] | amask[b * NA + a];
    __syncthreads();

    float g[HW];
#pragma unroll
    for (int w = 0; w < HW; ++w) g[w] = qhs[q][w] * ahs[a][w];

    const int wid = tid >> 6, lane = tid & 63;
    const float scale = 0.125f;  // 1/sqrt(64)
    float zacc = 0.f;

    for (int v = 0; v < NV; ++v) {
        if (vm[v]) {
            if (lane == 0) pvw[wid][v] = 0.f;
            continue;
        }
        float s = 0.f;
#pragma unroll
        for (int w = 0; w < HW; ++w) s += vhs[v][w] * g[w];
        float e = pm ? 0.f : __expf(s * scale);
        zacc += e;
        float r = e;
        r += __shfl_xor(r, 32);
        r += __shfl_xor(r, 16);
        r += __shfl_xor(r, 8);
        r += __shfl_xor(r, 4);
        r += __shfl_xor(r, 2);
        r += __shfl_xor(r, 1);
        if (lane == 0) pvw[wid][v] = r;
    }

    float pqp = zacc;
    pqp += __shfl_xor(pqp, 16);
    pqp += __shfl_xor(pqp, 8);
    pqp += __shfl_xor(pqp, 4);
    pqp += __shfl_xor(pqp, 2);
    pqp += __shfl_xor(pqp, 1);
    if ((lane & 31) == 0) pq_s[q] = pqp;

    float pap = zacc + __shfl_xor(zacc, 32);
    if (lane < 32) pa_w[wid][lane] = pap;
    __syncthreads();

    float pvf = 0.f, paf = 0.f;
    if (tid < NV) {
#pragma unroll
        for (int i = 0; i < 16; ++i) pvf += pvw[i][tid];
    }
    if (tid >= 128 && tid < 128 + NA) {
        int aa = tid - 128;
#pragma unroll
        for (int i = 0; i < 16; ++i) paf += pa_w[i][aa];
    }
    if (wid == 3) {
        float zv = (lane < NQ) ? pq_s[lane] : 0.f;
        zv += __shfl_xor(zv, 32);
        zv += __shfl_xor(zv, 16);
        zv += __shfl_xor(zv, 8);
        zv += __shfl_xor(zv, 4);
        zv += __shfl_xor(zv, 2);
        zv += __shfl_xor(zv, 1);
        if (lane == 0) zsh = zv;
    }
    __syncthreads();
    const float invZ = 1.0f / zsh;
    if (tid < NV) pvg[blockIdx.x * NV + tid] = pvf * invZ;
    if (tid >= 128 && tid < 128 + NA) pag[blockIdx.x * NA + (tid - 128)] = paf * invZ;
    if (tid >= 192 && tid < 192 + NQ) pqg[blockIdx.x * NQ + (tid - 192)] = pq_s[tid - 192] * invZ;
}

// ---------------------------------------------------------------------------
extern "C" void kernel_launch(void* const* d_in, const int* in_sizes, int n_in,
                              void* d_out, int out_size, void* d_ws, size_t ws_size,
                              hipStream_t stream)
{
    const float* v     = (const float*)d_in[0];
    const float* q     = (const float*)d_in[1];
    const float* a     = (const float*)d_in[2];
    const int*   vmask = (const int*)d_in[3];
    const int*   qmask = (const int*)d_in[4];
    const int*   amask = (const int*)d_in[5];
    const float* Wv  = (const float*)d_in[6];
    const float* bv  = (const float*)d_in[7];
    const float* Wq  = (const float*)d_in[8];
    const float* bq  = (const float*)d_in[9];
    const float* Wa  = (const float*)d_in[10];
    const float* ba  = (const float*)d_in[11];
    const float* Wvo = (const float*)d_in[12];
    const float* bvo = (const float*)d_in[13];
    const float* Wqo = (const float*)d_in[14];
    const float* bqo = (const float*)d_in[15];
    const float* Wao = (const float*)d_in[16];
    const float* bao = (const float*)d_in[17];
    float* out = (float*)d_out;          // reference output dtype is FLOAT32

    unsigned short* wsu = (unsigned short*)d_ws;
    unsigned short* vbf   = wsu;                    // 2457600
    unsigned short* qbf   = vbf + VP_ELEMS;         // 786432
    unsigned short* abf   = qbf + QP_ELEMS;         // 786432
    unsigned short* WtAll = abf + AP_ELEMS;         // 6 * 589824
    unsigned short* vpb   = WtAll + 6 * WELEMS;     // 2457600
    unsigned short* qpb   = vpb + VP_ELEMS;         // 786432
    unsigned short* apb   = qpb + QP_ELEMS;         // 786432
    float* pv = (float*)(apb + AP_ELEMS);           // 38400
    float* pq = pv + BB * NH * NV;                  // 12288
    float* pa = pq + BB * NH * NQ;                  // 12288
    // ws total ~23.5 MB

    conv_x<<<dim3(STOT / 4 / 256), dim3(256), 0, stream>>>(v, q, a, vbf);
    conv_wT<<<dim3(6 * 144), dim3(256), 0, stream>>>(Wv, Wq, Wa, Wvo, Wqo, Wao, WtAll);

    gemm_mfma<0><<<dim3(246), dim3(256), 0, stream>>>(
        vbf, qbf, abf,
        WtAll + 0 * WELEMS, WtAll + 1 * WELEMS, WtAll + 2 * WELEMS,
        bv, bq, ba,
        vpb, qpb, apb,
        nullptr, nullptr, nullptr,
        nullptr, nullptr, nullptr);

    attn_marginals<<<dim3(BB * NH), dim3(1024), 0, stream>>>(
        vpb, qpb, apb, vmask, qmask, amask, pv, pq, pa);

    gemm_mfma<1><<<dim3(246), dim3(256), 0, stream>>>(
        vpb, qpb, apb,
        WtAll + 3 * WELEMS, WtAll + 4 * WELEMS, WtAll + 5 * WELEMS,
        bvo, bqo, bao,
        nullptr, nullptr, nullptr,
        out, out + S1, out + S2,
        pv, pq, pa);
}

// Round 9
// 113.303 us; speedup vs baseline: 33.9482x; 2.0926x over previous
//
#include <hip/hip_runtime.h>
#include <hip/hip_bf16.h>

#define DIM 768
#define NH  12
#define HW  64
#define BB  32
#define NV  100
#define NQ  32
#define NA  32

#define VP_ELEMS (BB * NV * DIM)   // 2457600
#define QP_ELEMS (BB * NQ * DIM)   // 786432
#define AP_ELEMS (BB * NA * DIM)   // 786432
#define S1 (VP_ELEMS)
#define S2 (S1 + QP_ELEMS)
#define STOT (S2 + AP_ELEMS)       // 4030464
#define WELEMS (DIM * DIM)         // 589824

typedef __attribute__((ext_vector_type(8))) short     bf16x8;
typedef __attribute__((ext_vector_type(8))) unsigned short u16x8;
typedef __attribute__((ext_vector_type(4))) float     f32x4;

__device__ __forceinline__ float bf16r(float x) {
    return __bfloat162float(__float2bfloat16(x));
}
__device__ __forceinline__ unsigned short f2bu(float x) {
    __hip_bfloat16 h = __float2bfloat16(x);
    return *reinterpret_cast<unsigned short*>(&h);
}
__device__ __forceinline__ float bu2f(unsigned short u) {
    __hip_bfloat16 h;
    *reinterpret_cast<unsigned short*>(&h) = u;
    return __bfloat162float(h);
}

// ---------------------------------------------------------------------------
// Convert v|q|a (f32) -> contiguous bf16 buffer. 4 elems / thread.
// ---------------------------------------------------------------------------
__global__ __launch_bounds__(256) void conv_x(
    const float* __restrict__ v, const float* __restrict__ q,
    const float* __restrict__ a, unsigned short* __restrict__ dst)
{
    int idx = (blockIdx.x * 256 + threadIdx.x) * 4;
    if (idx >= STOT) return;
    const float* src; int off;
    if (idx < S1)      { src = v; off = idx; }
    else if (idx < S2) { src = q; off = idx - S1; }
    else               { src = a; off = idx - S2; }
    float4 f = *(const float4*)&src[off];
    ushort4 u;
    u.x = f2bu(f.x); u.y = f2bu(f.y); u.z = f2bu(f.z); u.w = f2bu(f.w);
    *(ushort4*)&dst[idx] = u;
}

// ---------------------------------------------------------------------------
// Convert 6 weights (f32, [k][n]) -> bf16 TRANSPOSED [n][k], via 64x64 LDS
// tiles. 6 * 144 tiles. Coalesced read + coalesced write.
// ---------------------------------------------------------------------------
__global__ __launch_bounds__(256) void conv_wT(
    const float* __restrict__ W0, const float* __restrict__ W1,
    const float* __restrict__ W2, const float* __restrict__ W3,
    const float* __restrict__ W4, const float* __restrict__ W5,
    unsigned short* __restrict__ WtAll)
{
    const int widx = blockIdx.x / 144;
    const int t    = blockIdx.x % 144;
    const int tr = t / 12, tc = t % 12;
    const float* W = (widx == 0) ? W0 : (widx == 1) ? W1 : (widx == 2) ? W2
                   : (widx == 3) ? W3 : (widx == 4) ? W4 : W5;
    unsigned short* Wt = WtAll + (size_t)widx * WELEMS;

    __shared__ float tile[64][65];
    const int c = threadIdx.x & 63, r4 = threadIdx.x >> 6;
#pragma unroll
    for (int it = 0; it < 16; ++it) {
        int r = it * 4 + r4;
        tile[r][c] = W[(size_t)(tr * 64 + r) * DIM + tc * 64 + c];
    }
    __syncthreads();
#pragma unroll
    for (int it = 0; it < 16; ++it) {
        int r = it * 4 + r4;   // output n-offset
        Wt[(size_t)(tc * 64 + r) * DIM + tr * 64 + c] = f2bu(tile[c][r]);
    }
}

// ---------------------------------------------------------------------------
// Fused MFMA GEMM over 3 pointer-sets (v/q/a). Y = X @ W + bias.
// X: [M][768] bf16 row-major. Wt: [n][k] bf16 (transposed weight).
// 128x128 tile, 256 thr = 2x2 waves, each wave 4x4 frags of 16x16, BK=32.
// OUT=0: write bf16 Y.  OUT=1: write f32 out, scaled by marginal, bf16-rounded.
// ---------------------------------------------------------------------------
template <int OUT>
__global__ __launch_bounds__(256) void gemm_mfma(
    const unsigned short* __restrict__ X0, const unsigned short* __restrict__ X1,
    const unsigned short* __restrict__ X2,
    const unsigned short* __restrict__ W0, const unsigned short* __restrict__ W1,
    const unsigned short* __restrict__ W2,
    const float* __restrict__ c0, const float* __restrict__ c1, const float* __restrict__ c2,
    unsigned short* __restrict__ Y0, unsigned short* __restrict__ Y1,
    unsigned short* __restrict__ Y2,
    float* __restrict__ O0, float* __restrict__ O1, float* __restrict__ O2,
    const float* __restrict__ m0, const float* __restrict__ m1, const float* __restrict__ m2)
{
    __shared__ unsigned short As[128 * 32];
    __shared__ unsigned short Bs[128 * 32];

    const int t = blockIdx.x;
    int set, loc;
    if (t < 150)      { set = 0; loc = t; }
    else if (t < 198) { set = 1; loc = t - 150; }
    else              { set = 2; loc = t - 198; }
    const int tm = loc / 6, tn = loc % 6;

    const unsigned short* X  = (set == 0) ? X0 : (set == 1) ? X1 : X2;
    const unsigned short* Wt = (set == 0) ? W0 : (set == 1) ? W1 : W2;
    const float* bias        = (set == 0) ? c0 : (set == 1) ? c1 : c2;
    unsigned short* Y        = (set == 0) ? Y0 : (set == 1) ? Y1 : Y2;
    float* Out               = (set == 0) ? O0 : (set == 1) ? O1 : O2;
    const float* mg          = (set == 0) ? m0 : (set == 1) ? m1 : m2;
    const int S              = (set == 0) ? NV : NQ;

    const int tid  = threadIdx.x;
    const int lane = tid & 63;
    const int wave = tid >> 6;
    const int wr = wave >> 1, wc = wave & 1;
    const int bm = tm * 128, bn = tn * 128;

    const int srow0 = tid >> 2, skc = (tid & 3) << 3;

    f32x4 acc[4][4] = {};

    for (int k0 = 0; k0 < DIM; k0 += 32) {
        *(u16x8*)&As[srow0 * 32 + skc] =
            *(const u16x8*)&X[(size_t)(bm + srow0) * DIM + k0 + skc];
        *(u16x8*)&As[(srow0 + 64) * 32 + skc] =
            *(const u16x8*)&X[(size_t)(bm + srow0 + 64) * DIM + k0 + skc];
        *(u16x8*)&Bs[srow0 * 32 + skc] =
            *(const u16x8*)&Wt[(size_t)(bn + srow0) * DIM + k0 + skc];
        *(u16x8*)&Bs[(srow0 + 64) * 32 + skc] =
            *(const u16x8*)&Wt[(size_t)(bn + srow0 + 64) * DIM + k0 + skc];
        __syncthreads();

        bf16x8 af[4], bfr[4];
#pragma unroll
        for (int mi = 0; mi < 4; ++mi)
            af[mi] = *(const bf16x8*)&As[(wr * 64 + mi * 16 + (lane & 15)) * 32 + (lane >> 4) * 8];
#pragma unroll
        for (int ni = 0; ni < 4; ++ni)
            bfr[ni] = *(const bf16x8*)&Bs[(wc * 64 + ni * 16 + (lane & 15)) * 32 + (lane >> 4) * 8];
#pragma unroll
        for (int mi = 0; mi < 4; ++mi)
#pragma unroll
            for (int ni = 0; ni < 4; ++ni)
                acc[mi][ni] = __builtin_amdgcn_mfma_f32_16x16x32_bf16(
                    af[mi], bfr[ni], acc[mi][ni], 0, 0, 0);
        __syncthreads();
    }

    const int h = (bn + wc * 64) >> 6;   // uniform per wave
#pragma unroll
    for (int mi = 0; mi < 4; ++mi) {
#pragma unroll
        for (int r = 0; r < 4; ++r) {
            const int m = bm + wr * 64 + mi * 16 + (lane >> 4) * 4 + r;
            float mgv = 0.f;
            if (OUT) {
                const int bb = m / S, ss = m - bb * S;
                mgv = mg[(bb * NH + h) * S + ss];
            }
#pragma unroll
            for (int ni = 0; ni < 4; ++ni) {
                const int n = bn + wc * 64 + ni * 16 + (lane & 15);
                const float val = acc[mi][ni][r] + bias[n];
                if (!OUT) Y[(size_t)m * DIM + n] = f2bu(val);
                else      Out[(size_t)m * DIM + n] = bf16r(val * mgv);
            }
        }
    }
}

// ---------------------------------------------------------------------------
// MFMA marginal kernel. One block per (b,h), 256 thr = 4 waves.
// scores[100x1024] = Vh[100x64] @ G^T, G[pair][w] = qh[q][w]*ah[a][w].
// e = exp(score*scale) * vm[v] * qm[q] * am[a]  (mask-mults reproduce the
// reference's exp(-10000...) -> 0 exactly); marginals via shuffle trees.
// Frag/C layouts identical to the validated gemm_mfma above.
// ---------------------------------------------------------------------------
__global__ __launch_bounds__(256) void attn_marginals_mfma(
    const unsigned short* __restrict__ vp, const unsigned short* __restrict__ qp,
    const unsigned short* __restrict__ ap,
    const int* __restrict__ vmask, const int* __restrict__ qmask, const int* __restrict__ amask,
    float* __restrict__ pvg, float* __restrict__ pqg, float* __restrict__ pag)
{
    const int b = blockIdx.x / NH, h = blockIdx.x % NH;
    const int tid = threadIdx.x, lane = tid & 63, wave = tid >> 6;
    const int col = lane & 15, rg = lane >> 4;

    __shared__ unsigned short vhs[112 * 72];   // bf16, stride 72 (bank-uniform)
    __shared__ float qhs[NQ * 65];
    __shared__ float ahs[NA * 65];
    __shared__ unsigned short G[256 * 72];     // bf16 chunk of g rows
    __shared__ float vm_mul[112], qm_mul[NQ], am_mul[NA];
    __shared__ float pv_sh[112], pq_sh[NQ], pa_sh[NA];
    __shared__ float zsh;

    for (int i = tid; i < 112 * 8; i += 256) {
        int v = i >> 3, c = i & 7;
        u16x8 val = {};
        if (v < NV) val = *(const u16x8*)&vp[(size_t)(b * NV + v) * DIM + h * 64 + c * 8];
        *(u16x8*)&vhs[v * 72 + c * 8] = val;
    }
    for (int i = tid; i < NQ * 64; i += 256) {
        int s = i >> 6, w = i & 63;
        qhs[s * 65 + w] = bu2f(qp[(size_t)(b * NQ + s) * DIM + h * 64 + w]);
        ahs[s * 65 + w] = bu2f(ap[(size_t)(b * NA + s) * DIM + h * 64 + w]);
    }
    if (tid < 112) { vm_mul[tid] = (tid < NV && vmask[b * NV + tid] == 0) ? 1.f : 0.f; pv_sh[tid] = 0.f; }
    if (tid < NQ)  { qm_mul[tid] = qmask[b * NQ + tid] ? 0.f : 1.f; pq_sh[tid] = 0.f; }
    if (tid < NA)  { am_mul[tid] = amask[b * NA + tid] ? 0.f : 1.f; pa_sh[tid] = 0.f; }
    __syncthreads();

    // resident A fragments: 7 v-tiles x 2 k-steps
    bf16x8 af[7][2];
#pragma unroll
    for (int vt = 0; vt < 7; ++vt)
#pragma unroll
        for (int kk = 0; kk < 2; ++kk)
            af[vt][kk] = *(const bf16x8*)&vhs[(vt * 16 + col) * 72 + kk * 32 + rg * 8];

    float pvacc[7][4] = {};
    const float scale = 0.125f;   // 1/sqrt(64)

    for (int cb = 0; cb < 1024; cb += 256) {
        // build G rows: thread tid -> pair cb+tid
        {
            const int p = cb + tid;
            const int qi = p >> 5, ai = p & 31;
#pragma unroll
            for (int c = 0; c < 8; ++c) {
                u16x8 gv;
#pragma unroll
                for (int j = 0; j < 8; ++j) {
                    const int w = c * 8 + j;
                    gv[j] = f2bu(qhs[qi * 65 + w] * ahs[ai * 65 + w]);
                }
                *(u16x8*)&G[tid * 72 + c * 8] = gv;
            }
        }
        __syncthreads();

        // wave owns pairs [cb + wave*64, +64): 4 pair-tiles of 16
#pragma unroll
        for (int pt = 0; pt < 4; ++pt) {
            const int grow = wave * 64 + pt * 16 + col;
            bf16x8 bf0 = *(const bf16x8*)&G[grow * 72 + rg * 8];
            bf16x8 bf1 = *(const bf16x8*)&G[grow * 72 + 32 + rg * 8];
            f32x4 acc[7] = {};
#pragma unroll
            for (int vt = 0; vt < 7; ++vt) {
                acc[vt] = __builtin_amdgcn_mfma_f32_16x16x32_bf16(af[vt][0], bf0, acc[vt], 0, 0, 0);
                acc[vt] = __builtin_amdgcn_mfma_f32_16x16x32_bf16(af[vt][1], bf1, acc[vt], 0, 0, 0);
            }
            const int qi = ((cb + wave * 64) >> 5) + (pt >> 1);
            const float pmul = qm_mul[qi] * am_mul[(pt & 1) * 16 + col];
            float zp = 0.f;
#pragma unroll
            for (int vt = 0; vt < 7; ++vt) {
#pragma unroll
                for (int r = 0; r < 4; ++r) {
                    const float e = __expf(acc[vt][r] * scale) * vm_mul[vt * 16 + rg * 4 + r] * pmul;
                    pvacc[vt][r] += e;
                    zp += e;
                }
            }
            // sum over v (row-groups), then distribute
            zp += __shfl_xor(zp, 16);
            zp += __shfl_xor(zp, 32);
            if (lane < 16) atomicAdd(&pa_sh[(pt & 1) * 16 + lane], zp);
            float zq = zp;
            zq += __shfl_xor(zq, 8);
            zq += __shfl_xor(zq, 4);
            zq += __shfl_xor(zq, 2);
            zq += __shfl_xor(zq, 1);
            if (lane == 0) atomicAdd(&pq_sh[qi], zq);
        }
        __syncthreads();
    }

    // pv: reduce over pair-cols, then across waves via LDS atomics
#pragma unroll
    for (int vt = 0; vt < 7; ++vt) {
#pragma unroll
        for (int r = 0; r < 4; ++r) {
            float pvv = pvacc[vt][r];
            pvv += __shfl_xor(pvv, 1);
            pvv += __shfl_xor(pvv, 2);
            pvv += __shfl_xor(pvv, 4);
            pvv += __shfl_xor(pvv, 8);
            if (col == 0) atomicAdd(&pv_sh[vt * 16 + rg * 4 + r], pvv);
        }
    }
    __syncthreads();
    if (tid == 0) {
        float z = 0.f;
        for (int i = 0; i < NQ; ++i) z += pq_sh[i];
        zsh = z;
    }
    __syncthreads();
    const float invZ = 1.0f / zsh;
    if (tid < NV) pvg[blockIdx.x * NV + tid] = pv_sh[tid] * invZ;
    if (tid < NQ) pqg[blockIdx.x * NQ + tid] = pq_sh[tid] * invZ;
    if (tid < NA) pag[blockIdx.x * NA + tid] = pa_sh[tid] * invZ;
}

// ---------------------------------------------------------------------------
extern "C" void kernel_launch(void* const* d_in, const int* in_sizes, int n_in,
                              void* d_out, int out_size, void* d_ws, size_t ws_size,
                              hipStream_t stream)
{
    const float* v     = (const float*)d_in[0];
    const float* q     = (const float*)d_in[1];
    const float* a     = (const float*)d_in[2];
    const int*   vmask = (const int*)d_in[3];
    const int*   qmask = (const int*)d_in[4];
    const int*   amask = (const int*)d_in[5];
    const float* Wv  = (const float*)d_in[6];
    const float* bv  = (const float*)d_in[7];
    const float* Wq  = (const float*)d_in[8];
    const float* bq  = (const float*)d_in[9];
    const float* Wa  = (const float*)d_in[10];
    const float* ba  = (const float*)d_in[11];
    const float* Wvo = (const float*)d_in[12];
    const float* bvo = (const float*)d_in[13];
    const float* Wqo = (const float*)d_in[14];
    const float* bqo = (const float*)d_in[15];
    const float* Wao = (const float*)d_in[16];
    const float* bao = (const float*)d_in[17];
    float* out = (float*)d_out;          // reference output dtype is FLOAT32

    unsigned short* wsu = (unsigned short*)d_ws;
    unsigned short* vbf   = wsu;                    // 2457600
    unsigned short* qbf   = vbf + VP_ELEMS;         // 786432
    unsigned short* abf   = qbf + QP_ELEMS;         // 786432
    unsigned short* WtAll = abf + AP_ELEMS;         // 6 * 589824
    unsigned short* vpb   = WtAll + 6 * WELEMS;     // 2457600
    unsigned short* qpb   = vpb + VP_ELEMS;         // 786432
    unsigned short* apb   = qpb + QP_ELEMS;         // 786432
    float* pv = (float*)(apb + AP_ELEMS);           // 38400
    float* pq = pv + BB * NH * NV;                  // 12288
    float* pa = pq + BB * NH * NQ;                  // 12288

    conv_x<<<dim3(STOT / 4 / 256), dim3(256), 0, stream>>>(v, q, a, vbf);
    conv_wT<<<dim3(6 * 144), dim3(256), 0, stream>>>(Wv, Wq, Wa, Wvo, Wqo, Wao, WtAll);

    gemm_mfma<0><<<dim3(246), dim3(256), 0, stream>>>(
        vbf, qbf, abf,
        WtAll + 0 * WELEMS, WtAll + 1 * WELEMS, WtAll + 2 * WELEMS,
        bv, bq, ba,
        vpb, qpb, apb,
        nullptr, nullptr, nullptr,
        nullptr, nullptr, nullptr);

    attn_marginals_mfma<<<dim3(BB * NH), dim3(256), 0, stream>>>(
        vpb, qpb, apb, vmask, qmask, amask, pv, pq, pa);

    gemm_mfma<1><<<dim3(246), dim3(256), 0, stream>>>(
        vpb, qpb, apb,
        WtAll + 3 * WELEMS, WtAll + 4 * WELEMS, WtAll + 5 * WELEMS,
        bvo, bqo, bao,
        nullptr, nullptr, nullptr,
        out, out + S1, out + S2,
        pv, pq, pa);
}

// Round 10
// 105.640 us; speedup vs baseline: 36.4107x; 1.0725x over previous
//
#include <hip/hip_runtime.h>
#include <hip/hip_bf16.h>

#define DIM 768
#define NH  12
#define HW  64
#define BB  32
#define NV  100
#define NQ  32
#define NA  32

#define VP_ELEMS (BB * NV * DIM)   // 2457600
#define QP_ELEMS (BB * NQ * DIM)   // 786432
#define AP_ELEMS (BB * NA * DIM)   // 786432
#define S1 (VP_ELEMS)
#define S2 (S1 + QP_ELEMS)
#define WELEMS (DIM * DIM)         // 589824
#define NBH (BB * NH)              // 384

typedef __attribute__((ext_vector_type(8))) short     bf16x8;
typedef __attribute__((ext_vector_type(8))) unsigned short u16x8;
typedef __attribute__((ext_vector_type(4))) float     f32x4;

__device__ __forceinline__ float bf16r(float x) {
    return __bfloat162float(__float2bfloat16(x));
}
__device__ __forceinline__ unsigned short f2bu(float x) {
    __hip_bfloat16 h = __float2bfloat16(x);
    return *reinterpret_cast<unsigned short*>(&h);
}
__device__ __forceinline__ float bu2f(unsigned short u) {
    __hip_bfloat16 h;
    *reinterpret_cast<unsigned short*>(&h) = u;
    return __bfloat162float(h);
}

// ---------------------------------------------------------------------------
// Convert 6 weights (f32, [k][n]) -> bf16 TRANSPOSED [n][k], via 64x64 LDS
// tiles. Coalesced read + coalesced write.
// ---------------------------------------------------------------------------
__global__ __launch_bounds__(256) void conv_wT(
    const float* __restrict__ W0, const float* __restrict__ W1,
    const float* __restrict__ W2, const float* __restrict__ W3,
    const float* __restrict__ W4, const float* __restrict__ W5,
    unsigned short* __restrict__ WtAll)
{
    const int widx = blockIdx.x / 144;
    const int t    = blockIdx.x % 144;
    const int tr = t / 12, tc = t % 12;
    const float* W = (widx == 0) ? W0 : (widx == 1) ? W1 : (widx == 2) ? W2
                   : (widx == 3) ? W3 : (widx == 4) ? W4 : W5;
    unsigned short* Wt = WtAll + (size_t)widx * WELEMS;

    __shared__ float tile[64][65];
    const int c = threadIdx.x & 63, r4 = threadIdx.x >> 6;
#pragma unroll
    for (int it = 0; it < 16; ++it) {
        int r = it * 4 + r4;
        tile[r][c] = W[(size_t)(tr * 64 + r) * DIM + tc * 64 + c];
    }
    __syncthreads();
#pragma unroll
    for (int it = 0; it < 16; ++it) {
        int r = it * 4 + r4;
        Wt[(size_t)(tc * 64 + r) * DIM + tr * 64 + c] = f2bu(tile[c][r]);
    }
}

// ---------------------------------------------------------------------------
// MFMA GEMM over 3 pointer-sets. Y = X @ W + bias.
// 64x128 tile (MxN), 256 thr = 4 waves; each wave 64x32 (4x2 frags), BK=32.
// OUT=0: X is f32 (converted in A-staging), writes bf16 Y.
// OUT=1: X is bf16, writes f32 out scaled by marginal, bf16-rounded.
// Tiles: set0 50x6=[0,300), set1 16x6=[300,396), set2 16x6=[396,492).
// ---------------------------------------------------------------------------
template <int OUT>
__global__ __launch_bounds__(256) void gemm_mfma(
    const void* __restrict__ X0v, const void* __restrict__ X1v, const void* __restrict__ X2v,
    const unsigned short* __restrict__ W0, const unsigned short* __restrict__ W1,
    const unsigned short* __restrict__ W2,
    const float* __restrict__ c0, const float* __restrict__ c1, const float* __restrict__ c2,
    unsigned short* __restrict__ Y0, unsigned short* __restrict__ Y1,
    unsigned short* __restrict__ Y2,
    float* __restrict__ O0, float* __restrict__ O1, float* __restrict__ O2,
    const float* __restrict__ m0, const float* __restrict__ m1, const float* __restrict__ m2)
{
    __shared__ unsigned short As[64 * 32];
    __shared__ unsigned short Bs[128 * 32];

    const int t = blockIdx.x;
    int set, loc;
    if (t < 300)      { set = 0; loc = t; }
    else if (t < 396) { set = 1; loc = t - 300; }
    else              { set = 2; loc = t - 396; }
    const int tm = loc / 6, tn = loc % 6;

    const void* Xv           = (set == 0) ? X0v : (set == 1) ? X1v : X2v;
    const unsigned short* Wt = (set == 0) ? W0 : (set == 1) ? W1 : W2;
    const float* bias        = (set == 0) ? c0 : (set == 1) ? c1 : c2;
    unsigned short* Y        = (set == 0) ? Y0 : (set == 1) ? Y1 : Y2;
    float* Out               = (set == 0) ? O0 : (set == 1) ? O1 : O2;
    const float* mg          = (set == 0) ? m0 : (set == 1) ? m1 : m2;
    const int S              = (set == 0) ? NV : NQ;

    const int tid = threadIdx.x, lane = tid & 63, wave = tid >> 6;
    const int col = lane & 15, rg = lane >> 4;
    const int bm = tm * 64, bn = tn * 128;

    const int arow = tid >> 2, akc = (tid & 3) << 3;   // A: 8 bf16 / thread
    const int brow = tid >> 1, bkc = (tid & 1) << 4;   // B: 16 bf16 / thread

    f32x4 acc[4][2] = {};

    for (int k0 = 0; k0 < DIM; k0 += 32) {
        if (OUT == 0) {
            const float* Xf = (const float*)Xv;
            const float4 f0 = *(const float4*)&Xf[(size_t)(bm + arow) * DIM + k0 + akc];
            const float4 f1 = *(const float4*)&Xf[(size_t)(bm + arow) * DIM + k0 + akc + 4];
            u16x8 u;
            u[0] = f2bu(f0.x); u[1] = f2bu(f0.y); u[2] = f2bu(f0.z); u[3] = f2bu(f0.w);
            u[4] = f2bu(f1.x); u[5] = f2bu(f1.y); u[6] = f2bu(f1.z); u[7] = f2bu(f1.w);
            *(u16x8*)&As[arow * 32 + akc] = u;
        } else {
            const unsigned short* Xb = (const unsigned short*)Xv;
            *(u16x8*)&As[arow * 32 + akc] =
                *(const u16x8*)&Xb[(size_t)(bm + arow) * DIM + k0 + akc];
        }
        *(u16x8*)&Bs[brow * 32 + bkc] =
            *(const u16x8*)&Wt[(size_t)(bn + brow) * DIM + k0 + bkc];
        *(u16x8*)&Bs[brow * 32 + bkc + 8] =
            *(const u16x8*)&Wt[(size_t)(bn + brow) * DIM + k0 + bkc + 8];
        __syncthreads();

        bf16x8 af[4], bfr[2];
#pragma unroll
        for (int mi = 0; mi < 4; ++mi)
            af[mi] = *(const bf16x8*)&As[(mi * 16 + col) * 32 + rg * 8];
#pragma unroll
        for (int ni = 0; ni < 2; ++ni)
            bfr[ni] = *(const bf16x8*)&Bs[(wave * 32 + ni * 16 + col) * 32 + rg * 8];
#pragma unroll
        for (int mi = 0; mi < 4; ++mi)
#pragma unroll
            for (int ni = 0; ni < 2; ++ni)
                acc[mi][ni] = __builtin_amdgcn_mfma_f32_16x16x32_bf16(
                    af[mi], bfr[ni], acc[mi][ni], 0, 0, 0);
        __syncthreads();
    }

    // C layout (validated): n-col = lane&15, m-row = (lane>>4)*4 + r
    const int h = (bn + wave * 32) >> 6;   // uniform per wave
#pragma unroll
    for (int mi = 0; mi < 4; ++mi) {
#pragma unroll
        for (int r = 0; r < 4; ++r) {
            const int m = bm + mi * 16 + rg * 4 + r;
            float mgv = 0.f;
            if (OUT) {
                const int bb = m / S, ss = m - bb * S;
                mgv = mg[(bb * NH + h) * S + ss];
            }
#pragma unroll
            for (int ni = 0; ni < 2; ++ni) {
                const int n = bn + wave * 32 + ni * 16 + col;
                const float val = acc[mi][ni][r] + bias[n];
                if (!OUT) Y[(size_t)m * DIM + n] = f2bu(val);
                else      Out[(size_t)m * DIM + n] = bf16r(val * mgv);
            }
        }
    }
}

// ---------------------------------------------------------------------------
// MFMA marginal kernel v2. Grid = NBH*2; block (bh, half) handles 512 pairs
// (pair-tiles [half*32, half*32+32)), 256 thr = 4 waves, 8 tiles/wave.
// B-fragments built per-lane from broadcast qhs/ahs reads (no G tile, no
// inner-loop syncs). All reductions in registers until kernel end.
// Halves are q-disjoint -> direct pq writes; pv/pa via per-half partials.
// ---------------------------------------------------------------------------
__global__ __launch_bounds__(256) void attn_marginals_mfma(
    const unsigned short* __restrict__ vp, const unsigned short* __restrict__ qp,
    const unsigned short* __restrict__ ap,
    const int* __restrict__ vmask, const int* __restrict__ qmask, const int* __restrict__ amask,
    float* __restrict__ pv_part, float* __restrict__ pa_part, float* __restrict__ pq_raw)
{
    const int bh = blockIdx.x >> 1, half = blockIdx.x & 1;
    const int b = bh / NH, h = bh % NH;
    const int tid = threadIdx.x, lane = tid & 63, wave = tid >> 6;
    const int col = lane & 15, rg = lane >> 4;

    __shared__ unsigned short vhs[112 * 72];   // bf16
    __shared__ float qhs[NQ * 68];
    __shared__ float ahs[NA * 68];
    __shared__ float vm_mul[112], qm_mul[NQ], am_mul[NA];
    __shared__ float pv_sh[112], pa_sh[NA];

    for (int i = tid; i < 112 * 8; i += 256) {
        int v = i >> 3, c = i & 7;
        u16x8 val = {};
        if (v < NV) val = *(const u16x8*)&vp[(size_t)(b * NV + v) * DIM + h * 64 + c * 8];
        *(u16x8*)&vhs[v * 72 + c * 8] = val;
    }
    {   // 256 threads, exactly one u16x8 each for q and a
        const int s = tid >> 3, c = tid & 7;
        const u16x8 qv = *(const u16x8*)&qp[(size_t)(b * NQ + s) * DIM + h * 64 + c * 8];
        const u16x8 av = *(const u16x8*)&ap[(size_t)(b * NA + s) * DIM + h * 64 + c * 8];
#pragma unroll
        for (int j = 0; j < 8; ++j) {
            qhs[s * 68 + c * 8 + j] = bu2f(qv[j]);
            ahs[s * 68 + c * 8 + j] = bu2f(av[j]);
        }
    }
    if (tid < 112) { vm_mul[tid] = (tid < NV && vmask[b * NV + tid] == 0) ? 1.f : 0.f; pv_sh[tid] = 0.f; }
    if (tid < NQ)  { qm_mul[tid] = qmask[b * NQ + tid] ? 0.f : 1.f; }
    if (tid < NA)  { am_mul[tid] = amask[b * NA + tid] ? 0.f : 1.f; pa_sh[tid] = 0.f; }
    __syncthreads();

    bf16x8 af[7][2];
#pragma unroll
    for (int vt = 0; vt < 7; ++vt) {
        af[vt][0] = *(const bf16x8*)&vhs[(vt * 16 + col) * 72 + rg * 8];
        af[vt][1] = *(const bf16x8*)&vhs[(vt * 16 + col) * 72 + 32 + rg * 8];
    }

    const float am01[2] = { am_mul[col], am_mul[16 + col] };
    const int qbase = half * 16 + wave * 4;
    const float qmw[4] = { qm_mul[qbase], qm_mul[qbase + 1], qm_mul[qbase + 2], qm_mul[qbase + 3] };

    float pvacc[7][4] = {};
    float za0 = 0.f, za1 = 0.f;
    float zq[4] = {};
    const float sc2 = 0.125f * 1.44269504088896f;   // scale * log2(e)

#pragma unroll
    for (int i = 0; i < 8; ++i) {
        const int ptg = half * 32 + wave * 8 + i;
        const int qi = ptg >> 1;
        const int ai = ((i & 1) << 4) + col;
        bf16x8 bf0, bf1;
#pragma unroll
        for (int j = 0; j < 8; ++j) {
            bf0[j] = (short)f2bu(qhs[qi * 68 + rg * 8 + j]      * ahs[ai * 68 + rg * 8 + j]);
            bf1[j] = (short)f2bu(qhs[qi * 68 + 32 + rg * 8 + j] * ahs[ai * 68 + 32 + rg * 8 + j]);
        }
        f32x4 acc[7] = {};
#pragma unroll
        for (int vt = 0; vt < 7; ++vt) {
            acc[vt] = __builtin_amdgcn_mfma_f32_16x16x32_bf16(af[vt][0], bf0, acc[vt], 0, 0, 0);
            acc[vt] = __builtin_amdgcn_mfma_f32_16x16x32_bf16(af[vt][1], bf1, acc[vt], 0, 0, 0);
        }
        const float pmul = qmw[i >> 1] * am01[i & 1];
#pragma unroll
        for (int vt = 0; vt < 7; ++vt) {
#pragma unroll
            for (int r = 0; r < 4; ++r) {
                const float e = exp2f(acc[vt][r] * sc2) * vm_mul[vt * 16 + rg * 4 + r] * pmul;
                pvacc[vt][r] += e;
                if (i & 1) za1 += e; else za0 += e;
                zq[i >> 1] += e;
            }
        }
    }

    // end-of-kernel reductions
#pragma unroll
    for (int vt = 0; vt < 7; ++vt) {
#pragma unroll
        for (int r = 0; r < 4; ++r) {
            float x = pvacc[vt][r];
            x += __shfl_xor(x, 1); x += __shfl_xor(x, 2);
            x += __shfl_xor(x, 4); x += __shfl_xor(x, 8);
            if (col == 0) atomicAdd(&pv_sh[vt * 16 + rg * 4 + r], x);
        }
    }
    {
        float x = za0;
        x += __shfl_xor(x, 16); x += __shfl_xor(x, 32);
        if (rg == 0) atomicAdd(&pa_sh[col], x);
        float y = za1;
        y += __shfl_xor(y, 16); y += __shfl_xor(y, 32);
        if (rg == 0) atomicAdd(&pa_sh[16 + col], y);
    }
#pragma unroll
    for (int j = 0; j < 4; ++j) {
        float x = zq[j];
        x += __shfl_xor(x, 1); x += __shfl_xor(x, 2); x += __shfl_xor(x, 4);
        x += __shfl_xor(x, 8); x += __shfl_xor(x, 16); x += __shfl_xor(x, 32);
        if (lane == 0) pq_raw[bh * NQ + qbase + j] = x;   // unique writer per qi
    }
    __syncthreads();
    if (tid < 112) pv_part[(size_t)(bh * 2 + half) * 112 + tid] = pv_sh[tid];
    if (tid < NA)  pa_part[(size_t)(bh * 2 + half) * NA + tid] = pa_sh[tid];
}

// ---------------------------------------------------------------------------
// Normalize: Z = sum(pq_raw), combine halves, scale by 1/Z.
// ---------------------------------------------------------------------------
__global__ __launch_bounds__(128) void normalize_marg(
    const float* __restrict__ pv_part, const float* __restrict__ pa_part,
    float* __restrict__ pq, float* __restrict__ pv, float* __restrict__ pa)
{
    const int bh = blockIdx.x;
    const int tid = threadIdx.x, lane = tid & 63;
    __shared__ float zsh;
    if (tid < 64) {
        float x = (lane < NQ) ? pq[bh * NQ + lane] : 0.f;
        x += __shfl_xor(x, 1); x += __shfl_xor(x, 2); x += __shfl_xor(x, 4);
        x += __shfl_xor(x, 8); x += __shfl_xor(x, 16); x += __shfl_xor(x, 32);
        if (lane == 0) zsh = x;
    }
    __syncthreads();
    const float invZ = 1.0f / zsh;
    if (tid < NV)
        pv[bh * NV + tid] = (pv_part[(size_t)(bh * 2) * 112 + tid]
                           + pv_part[(size_t)(bh * 2 + 1) * 112 + tid]) * invZ;
    if (tid < NQ) pq[bh * NQ + tid] *= invZ;
    if (tid < NA)
        pa[bh * NA + tid] = (pa_part[(size_t)(bh * 2) * NA + tid]
                           + pa_part[(size_t)(bh * 2 + 1) * NA + tid]) * invZ;
}

// ---------------------------------------------------------------------------
extern "C" void kernel_launch(void* const* d_in, const int* in_sizes, int n_in,
                              void* d_out, int out_size, void* d_ws, size_t ws_size,
                              hipStream_t stream)
{
    const float* v     = (const float*)d_in[0];
    const float* q     = (const float*)d_in[1];
    const float* a     = (const float*)d_in[2];
    const int*   vmask = (const int*)d_in[3];
    const int*   qmask = (const int*)d_in[4];
    const int*   amask = (const int*)d_in[5];
    const float* Wv  = (const float*)d_in[6];
    const float* bv  = (const float*)d_in[7];
    const float* Wq  = (const float*)d_in[8];
    const float* bq  = (const float*)d_in[9];
    const float* Wa  = (const float*)d_in[10];
    const float* ba  = (const float*)d_in[11];
    const float* Wvo = (const float*)d_in[12];
    const float* bvo = (const float*)d_in[13];
    const float* Wqo = (const float*)d_in[14];
    const float* bqo = (const float*)d_in[15];
    const float* Wao = (const float*)d_in[16];
    const float* bao = (const float*)d_in[17];
    float* out = (float*)d_out;          // reference output dtype is FLOAT32

    unsigned short* wsu = (unsigned short*)d_ws;
    unsigned short* WtAll = wsu;                    // 6 * 589824
    unsigned short* vpb   = WtAll + 6 * WELEMS;     // 2457600
    unsigned short* qpb   = vpb + VP_ELEMS;         // 786432
    unsigned short* apb   = qpb + QP_ELEMS;         // 786432
    float* fbase   = (float*)(apb + AP_ELEMS);
    float* pv_part = fbase;                         // 384*2*112 = 86016
    float* pa_part = pv_part + NBH * 2 * 112;       // 384*2*32  = 24576
    float* pq      = pa_part + NBH * 2 * NA;        // 384*32    = 12288
    float* pv      = pq + NBH * NQ;                 // 384*100   = 38400
    float* pa      = pv + NBH * NV;                 // 384*32    = 12288
    // ws total ~15.8 MB

    conv_wT<<<dim3(6 * 144), dim3(256), 0, stream>>>(Wv, Wq, Wa, Wvo, Wqo, Wao, WtAll);

    gemm_mfma<0><<<dim3(492), dim3(256), 0, stream>>>(
        v, q, a,
        WtAll + 0 * WELEMS, WtAll + 1 * WELEMS, WtAll + 2 * WELEMS,
        bv, bq, ba,
        vpb, qpb, apb,
        nullptr, nullptr, nullptr,
        nullptr, nullptr, nullptr);

    attn_marginals_mfma<<<dim3(NBH * 2), dim3(256), 0, stream>>>(
        vpb, qpb, apb, vmask, qmask, amask, pv_part, pa_part, pq);

    normalize_marg<<<dim3(NBH), dim3(128), 0, stream>>>(pv_part, pa_part, pq, pv, pa);

    gemm_mfma<1><<<dim3(492), dim3(256), 0, stream>>>(
        vpb, qpb, apb,
        WtAll + 3 * WELEMS, WtAll + 4 * WELEMS, WtAll + 5 * WELEMS,
        bvo, bqo, bao,
        nullptr, nullptr, nullptr,
        out, out + S1, out + S2,
        pv, pq, pa);
}